// Round 1
// baseline (317.324 us; speedup 1.0000x reference)
//
#include <hip/hip_runtime.h>

// B=16, D=16, H=288, W=512, L=17 (fixed by setup_inputs)
#define BB   16
#define DD   16
#define NN   (288*512)     // 147456 pixels/image
#define LL   17
#define TPB  256
#define NREP 16            // LDS table replicas (4 lanes/replica)

#define PB   144           // accum blocks/image: 2304 blocks (~9/CU queued)
#define QB   (NN/4/PB)     // 256 quads/block -> 4 iters/wave
#define PBV  144           // var blocks/image: 1024 px/block one-shot

#define FSCALE 32768.0f
#define INV_FSCALE (1.0f/32768.0f)
#define SUMSCALE 4294967296.0     // 2^32 fixed-point for final loss accumulate

// ws layout: acc int[B][289] | u64 sum | u32 done   (one contiguous memset)

__global__ __launch_bounds__(TPB) void k_accum(const float* __restrict__ emb,
                                               const int* __restrict__ seg,
                                               int* __restrict__ acc) {
    __shared__ int tab[NREP * 289];   // pad-17 rows: injective label->bank (gcd(17,32)=1)
    const int tid  = threadIdx.x;
    const int b    = blockIdx.y;
    const int blk  = blockIdx.x;
    const int dgrp = tid >> 6;        // wave owns channels 4*dgrp..+3 (wave-uniform)
    const int j    = tid & 63;
    int* trep = tab + (j & (NREP - 1)) * 289;

    for (int i = tid; i < NREP * 289; i += TPB) tab[i] = 0;

    const float* embb = emb + (size_t)b * DD * NN;
    const int*   segb = seg + (size_t)b * NN;
    const float* r0 = embb + (size_t)(dgrp * 4 + 0) * NN;
    const float* r1 = embb + (size_t)(dgrp * 4 + 1) * NN;
    const float* r2 = embb + (size_t)(dgrp * 4 + 2) * NN;
    const float* r3 = embb + (size_t)(dgrp * 4 + 3) * NN;
    const int q0 = blk * QB;
    __syncthreads();

    // ---- 2-stage software pipeline: iter i+1 loads issue before iter i's
    // atomic block, keeping ~10 vector loads in flight per wave. ----
    int n = (q0 + j) * 4;
    int4   s4 = *(const int4*)(segb + n);
    float4 e0 = *(const float4*)(r0 + n);
    float4 e1 = *(const float4*)(r1 + n);
    float4 e2 = *(const float4*)(r2 + n);
    float4 e3 = *(const float4*)(r3 + n);

#pragma unroll
    for (int it = 0; it < QB / 64; ++it) {
        int4 s4n; float4 e0n, e1n, e2n, e3n;
        if (it + 1 < QB / 64) {
            const int nn_ = (q0 + (it + 1) * 64 + j) * 4;
            s4n = *(const int4*)(segb + nn_);
            e0n = *(const float4*)(r0 + nn_);
            e1n = *(const float4*)(r1 + nn_);
            e2n = *(const float4*)(r2 + nn_);
            e3n = *(const float4*)(r3 + nn_);
        }
        const int ch = dgrp * 4;
        // label 0 (background) contributes nothing to the loss: sums[0] and
        // cnt[0] feed only zero-weighted terms (wl[0]=0, present excludes 0),
        // so skip its atomics entirely (~1/17 of all LDS RMW traffic).
        // native ds_add_u32 (no return -> fire-and-forget), fixed-point 2^15
        if (s4.x) {
            const int o0 = s4.x * 17 + ch;
            atomicAdd(trep + o0 + 0, __float2int_rn(e0.x * FSCALE));
            atomicAdd(trep + o0 + 1, __float2int_rn(e1.x * FSCALE));
            atomicAdd(trep + o0 + 2, __float2int_rn(e2.x * FSCALE));
            atomicAdd(trep + o0 + 3, __float2int_rn(e3.x * FSCALE));
            if (dgrp == 0) atomicAdd(trep + s4.x * 17 + 16, 1);
        }
        if (s4.y) {
            const int o1 = s4.y * 17 + ch;
            atomicAdd(trep + o1 + 0, __float2int_rn(e0.y * FSCALE));
            atomicAdd(trep + o1 + 1, __float2int_rn(e1.y * FSCALE));
            atomicAdd(trep + o1 + 2, __float2int_rn(e2.y * FSCALE));
            atomicAdd(trep + o1 + 3, __float2int_rn(e3.y * FSCALE));
            if (dgrp == 0) atomicAdd(trep + s4.y * 17 + 16, 1);
        }
        if (s4.z) {
            const int o2 = s4.z * 17 + ch;
            atomicAdd(trep + o2 + 0, __float2int_rn(e0.z * FSCALE));
            atomicAdd(trep + o2 + 1, __float2int_rn(e1.z * FSCALE));
            atomicAdd(trep + o2 + 2, __float2int_rn(e2.z * FSCALE));
            atomicAdd(trep + o2 + 3, __float2int_rn(e3.z * FSCALE));
            if (dgrp == 0) atomicAdd(trep + s4.z * 17 + 16, 1);
        }
        if (s4.w) {
            const int o3 = s4.w * 17 + ch;
            atomicAdd(trep + o3 + 0, __float2int_rn(e0.w * FSCALE));
            atomicAdd(trep + o3 + 1, __float2int_rn(e1.w * FSCALE));
            atomicAdd(trep + o3 + 2, __float2int_rn(e2.w * FSCALE));
            atomicAdd(trep + o3 + 3, __float2int_rn(e3.w * FSCALE));
            if (dgrp == 0) atomicAdd(trep + s4.w * 17 + 16, 1);
        }
        s4 = s4n; e0 = e0n; e1 = e1n; e2 = e2n; e3 = e3n;
    }
    __syncthreads();

    for (int i = tid; i < 289; i += TPB) {
        int v = 0;
#pragma unroll
        for (int r = 0; r < NREP; ++r) v += tab[r * 289 + i];
        atomicAdd(acc + b * 289 + i, v);   // native global int atomic
    }
}

__global__ __launch_bounds__(TPB) void k_var(const float* __restrict__ emb,
                                             const int* __restrict__ seg,
                                             const int* __restrict__ acc,
                                             unsigned long long* __restrict__ gsum,
                                             unsigned int* __restrict__ gdone,
                                             float* __restrict__ out) {
    __shared__ float m[289];     // padded [17][17]: conflict-free random lookups
    __shared__ float wl[17];
    __shared__ float wsum[TPB / 64];
    const int tid = threadIdx.x;
    const int b = blockIdx.y;

    for (int i = tid; i < 289; i += TPB) {
        const int raw = acc[b * 289 + i];
        m[i] = (i % 17 == 16) ? (float)raw : (float)raw * INV_FSCALE;
    }
    __syncthreads();
    for (int i = tid; i < 272; i += TPB) {
        const int l = i >> 4, d = i & 15;
        m[l * 17 + d] /= fmaxf(m[l * 17 + 16], 1.f);
    }
    __syncthreads();

    int nl = 0;
#pragma unroll
    for (int l = 1; l < LL; ++l) nl += (m[l * 17 + 16] > 0.f) ? 1 : 0;
    const float nlf = (float)nl;
    if (tid < LL) {
        const bool pres = (tid != 0) && (m[tid * 17 + 16] > 0.f);
        wl[tid] = pres ? 1.f / (fmaxf(m[tid * 17 + 16], 1.f) * fmaxf(nlf, 1.f) * (float)BB)
                       : 0.f;
    }
    __syncthreads();

    const float* embb = emb + (size_t)b * DD * NN;
    const int*   segb = seg + (size_t)b * NN;

    const int n = blockIdx.x * (TPB * 4) + tid * 4;   // 144*1024 = NN exactly
    const int4 s4 = *(const int4*)(segb + n);
    const int o0 = s4.x * 17, o1 = s4.y * 17, o2 = s4.z * 17, o3 = s4.w * 17;
    float ss0 = 0.f, ss1 = 0.f, ss2 = 0.f, ss3 = 0.f;
#pragma unroll
    for (int d = 0; d < DD; ++d) {
        const float4 e = *(const float4*)(embb + (size_t)d * NN + n);
        const float d0 = e.x - m[o0 + d]; ss0 += d0 * d0;
        const float d1 = e.y - m[o1 + d]; ss1 += d1 * d1;
        const float d2 = e.z - m[o2 + d]; ss2 += d2 * d2;
        const float d3 = e.w - m[o3 + d]; ss3 += d3 * d3;
    }
    float accl = 0.f, t;
    t = fmaxf(sqrtf(fmaxf(ss0, 1e-12f)) - 0.5f, 0.f); accl += t * t * wl[s4.x];
    t = fmaxf(sqrtf(fmaxf(ss1, 1e-12f)) - 0.5f, 0.f); accl += t * t * wl[s4.y];
    t = fmaxf(sqrtf(fmaxf(ss2, 1e-12f)) - 0.5f, 0.f); accl += t * t * wl[s4.z];
    t = fmaxf(sqrtf(fmaxf(ss3, 1e-12f)) - 0.5f, 0.f); accl += t * t * wl[s4.w];

    // push (distance) term, once per image, folded into block-0's partial
    if (blockIdx.x == 0 && nl > 1) {
        float push = 0.f;
        for (int p = tid; p < 289; p += TPB) {
            const int i = p / 17, jj = p % 17;
            if (i != jj && i > 0 && jj > 0 && m[i*17+16] > 0.f && m[jj*17+16] > 0.f) {
                float ss = 0.f;
#pragma unroll
                for (int d = 0; d < DD; ++d) {
                    const float df = m[i*17+d] - m[jj*17+d];
                    ss += df * df;
                }
                const float u = fmaxf(1.5f - sqrtf(ss), 0.f);
                push += u * u;
            }
        }
        accl += push / (fmaxf(nlf * (nlf - 1.f), 1.f) * 2.f * (float)BB);
    }

#pragma unroll
    for (int off = 32; off; off >>= 1) accl += __shfl_down(accl, off, 64);
    if ((tid & 63) == 0) wsum[tid >> 6] = accl;
    __syncthreads();

    // fused finalization: deterministic fixed-point i64 accumulate; the last
    // block to arrive converts and writes the scalar output (saves k_final).
    if (tid == 0) {
        const float part = wsum[0] + wsum[1] + wsum[2] + wsum[3];   // >= 0
        const unsigned long long q =
            (unsigned long long)__double2ll_rn((double)part * SUMSCALE);
        atomicAdd(gsum, q);
        __threadfence();
        const unsigned int old = atomicAdd(gdone, 1u);
        if (old == (unsigned int)(BB * PBV) - 1u) {
            __threadfence();
            const unsigned long long s = atomicAdd(gsum, 0ULL);  // atomic read
            out[0] = (float)((double)s * (1.0 / SUMSCALE));
        }
    }
}

extern "C" void kernel_launch(void* const* d_in, const int* in_sizes, int n_in,
                              void* d_out, int out_size, void* d_ws, size_t ws_size,
                              hipStream_t stream) {
    const float* emb = (const float*)d_in[0];
    const int*   seg = (const int*)d_in[1];
    float* out = (float*)d_out;

    int* acc = (int*)d_ws;                                   // 16*289 ints = 18496 B
    unsigned long long* gsum = (unsigned long long*)((char*)d_ws + BB * 289 * 4);
    unsigned int* gdone = (unsigned int*)((char*)d_ws + BB * 289 * 4 + 8);

    // one contiguous clear: acc + gsum + gdone
    hipMemsetAsync(d_ws, 0, (size_t)BB * 289 * 4 + 16, stream);

    k_accum<<<dim3(PB, BB), TPB, 0, stream>>>(emb, seg, acc);
    k_var  <<<dim3(PBV, BB), TPB, 0, stream>>>(emb, seg, acc, gsum, gdone, out);
}

// Round 2
// 243.560 us; speedup vs baseline: 1.3029x; 1.3029x over previous
//
#include <hip/hip_runtime.h>

// B=16, D=16, H=288, W=512, L=17 (fixed by setup_inputs)
#define BB   16
#define DD   16
#define NN   (288*512)     // 147456 pixels/image
#define LL   17
#define TPB  256
#define NREP 16            // LDS table replicas (4 lanes/replica)

#define PB   144           // accum blocks/image: 2304 blocks (~9/CU queued)
#define QB   (NN/4/PB)     // 256 quads/block -> 4 iters/wave
#define PBV  144           // var blocks/image: 1024 px/block one-shot

#define FSCALE 32768.0f
#define INV_FSCALE (1.0f/32768.0f)

// ws layout: acc int[B][289] | vpart float[B*PBV]

__global__ __launch_bounds__(TPB) void k_accum(const float* __restrict__ emb,
                                               const int* __restrict__ seg,
                                               int* __restrict__ acc) {
    __shared__ int tab[NREP * 289];   // pad-17 rows: injective label->bank (gcd(17,32)=1)
    const int tid  = threadIdx.x;
    const int b    = blockIdx.y;
    const int blk  = blockIdx.x;
    const int dgrp = tid >> 6;        // wave owns channels 4*dgrp..+3 (wave-uniform)
    const int j    = tid & 63;
    int* trep = tab + (j & (NREP - 1)) * 289;

    for (int i = tid; i < NREP * 289; i += TPB) tab[i] = 0;

    const float* embb = emb + (size_t)b * DD * NN;
    const int*   segb = seg + (size_t)b * NN;
    const float* r0 = embb + (size_t)(dgrp * 4 + 0) * NN;
    const float* r1 = embb + (size_t)(dgrp * 4 + 1) * NN;
    const float* r2 = embb + (size_t)(dgrp * 4 + 2) * NN;
    const float* r3 = embb + (size_t)(dgrp * 4 + 3) * NN;
    const int q0 = blk * QB;
    __syncthreads();

    // ---- 2-stage software pipeline: iter i+1 loads issue before iter i's
    // atomic block, keeping ~10 vector loads in flight per wave. ----
    int n = (q0 + j) * 4;
    int4   s4 = *(const int4*)(segb + n);
    float4 e0 = *(const float4*)(r0 + n);
    float4 e1 = *(const float4*)(r1 + n);
    float4 e2 = *(const float4*)(r2 + n);
    float4 e3 = *(const float4*)(r3 + n);

#pragma unroll
    for (int it = 0; it < QB / 64; ++it) {
        int4 s4n; float4 e0n, e1n, e2n, e3n;
        if (it + 1 < QB / 64) {
            const int nn_ = (q0 + (it + 1) * 64 + j) * 4;
            s4n = *(const int4*)(segb + nn_);
            e0n = *(const float4*)(r0 + nn_);
            e1n = *(const float4*)(r1 + nn_);
            e2n = *(const float4*)(r2 + nn_);
            e3n = *(const float4*)(r3 + nn_);
        }
        const int ch = dgrp * 4;
        // label 0 (background) contributes nothing to the loss: sums[0] and
        // cnt[0] feed only zero-weighted terms (wl[0]=0, present excludes 0),
        // so skip its atomics entirely (~1/17 of all LDS RMW traffic).
        // native ds_add_u32 (no return -> fire-and-forget), fixed-point 2^15
        if (s4.x) {
            const int o0 = s4.x * 17 + ch;
            atomicAdd(trep + o0 + 0, __float2int_rn(e0.x * FSCALE));
            atomicAdd(trep + o0 + 1, __float2int_rn(e1.x * FSCALE));
            atomicAdd(trep + o0 + 2, __float2int_rn(e2.x * FSCALE));
            atomicAdd(trep + o0 + 3, __float2int_rn(e3.x * FSCALE));
            if (dgrp == 0) atomicAdd(trep + s4.x * 17 + 16, 1);
        }
        if (s4.y) {
            const int o1 = s4.y * 17 + ch;
            atomicAdd(trep + o1 + 0, __float2int_rn(e0.y * FSCALE));
            atomicAdd(trep + o1 + 1, __float2int_rn(e1.y * FSCALE));
            atomicAdd(trep + o1 + 2, __float2int_rn(e2.y * FSCALE));
            atomicAdd(trep + o1 + 3, __float2int_rn(e3.y * FSCALE));
            if (dgrp == 0) atomicAdd(trep + s4.y * 17 + 16, 1);
        }
        if (s4.z) {
            const int o2 = s4.z * 17 + ch;
            atomicAdd(trep + o2 + 0, __float2int_rn(e0.z * FSCALE));
            atomicAdd(trep + o2 + 1, __float2int_rn(e1.z * FSCALE));
            atomicAdd(trep + o2 + 2, __float2int_rn(e2.z * FSCALE));
            atomicAdd(trep + o2 + 3, __float2int_rn(e3.z * FSCALE));
            if (dgrp == 0) atomicAdd(trep + s4.z * 17 + 16, 1);
        }
        if (s4.w) {
            const int o3 = s4.w * 17 + ch;
            atomicAdd(trep + o3 + 0, __float2int_rn(e0.w * FSCALE));
            atomicAdd(trep + o3 + 1, __float2int_rn(e1.w * FSCALE));
            atomicAdd(trep + o3 + 2, __float2int_rn(e2.w * FSCALE));
            atomicAdd(trep + o3 + 3, __float2int_rn(e3.w * FSCALE));
            if (dgrp == 0) atomicAdd(trep + s4.w * 17 + 16, 1);
        }
        s4 = s4n; e0 = e0n; e1 = e1n; e2 = e2n; e3 = e3n;
    }
    __syncthreads();

    for (int i = tid; i < 289; i += TPB) {
        int v = 0;
#pragma unroll
        for (int r = 0; r < NREP; ++r) v += tab[r * 289 + i];
        atomicAdd(acc + b * 289 + i, v);   // native global int atomic
    }
}

// __launch_bounds__(256, 4): cap ~128 VGPRs so the 16 float4 emb loads for a
// quad can ALL be in flight (64 VGPRs of payload). At VGPR=40 (prev round)
// the compiler serialized load->wait->consume: 107us, VALUBusy 5%, 1.5 TB/s.
__global__ __launch_bounds__(TPB, 4) void k_var(const float* __restrict__ emb,
                                                const int* __restrict__ seg,
                                                const int* __restrict__ acc,
                                                float* __restrict__ vpart) {
    __shared__ float m[289];     // padded [17][17]: conflict-free random lookups
    __shared__ float wl[17];
    __shared__ float wsum[TPB / 64];
    const int tid = threadIdx.x;
    const int b = blockIdx.y;

    for (int i = tid; i < 289; i += TPB) {
        const int raw = acc[b * 289 + i];
        m[i] = (i % 17 == 16) ? (float)raw : (float)raw * INV_FSCALE;
    }
    __syncthreads();
    for (int i = tid; i < 272; i += TPB) {
        const int l = i >> 4, d = i & 15;
        m[l * 17 + d] /= fmaxf(m[l * 17 + 16], 1.f);
    }
    __syncthreads();

    int nl = 0;
#pragma unroll
    for (int l = 1; l < LL; ++l) nl += (m[l * 17 + 16] > 0.f) ? 1 : 0;
    const float nlf = (float)nl;
    if (tid < LL) {
        const bool pres = (tid != 0) && (m[tid * 17 + 16] > 0.f);
        wl[tid] = pres ? 1.f / (fmaxf(m[tid * 17 + 16], 1.f) * fmaxf(nlf, 1.f) * (float)BB)
                       : 0.f;
    }
    __syncthreads();

    const float* embb = emb + (size_t)b * DD * NN;
    const int*   segb = seg + (size_t)b * NN;

    const int n = blockIdx.x * (TPB * 4) + tid * 4;   // 144*1024 = NN exactly
    const int4 s4 = *(const int4*)(segb + n);

    // preload ALL 16 channel float4s (independent loads -> one vmcnt ladder)
    float4 e[DD];
#pragma unroll
    for (int d = 0; d < DD; ++d)
        e[d] = *(const float4*)(embb + (size_t)d * NN + n);

    const int o0 = s4.x * 17, o1 = s4.y * 17, o2 = s4.z * 17, o3 = s4.w * 17;
    float ss0 = 0.f, ss1 = 0.f, ss2 = 0.f, ss3 = 0.f;
#pragma unroll
    for (int d = 0; d < DD; ++d) {
        const float d0 = e[d].x - m[o0 + d]; ss0 += d0 * d0;
        const float d1 = e[d].y - m[o1 + d]; ss1 += d1 * d1;
        const float d2 = e[d].z - m[o2 + d]; ss2 += d2 * d2;
        const float d3 = e[d].w - m[o3 + d]; ss3 += d3 * d3;
    }
    float accl = 0.f, t;
    t = fmaxf(sqrtf(fmaxf(ss0, 1e-12f)) - 0.5f, 0.f); accl += t * t * wl[s4.x];
    t = fmaxf(sqrtf(fmaxf(ss1, 1e-12f)) - 0.5f, 0.f); accl += t * t * wl[s4.y];
    t = fmaxf(sqrtf(fmaxf(ss2, 1e-12f)) - 0.5f, 0.f); accl += t * t * wl[s4.z];
    t = fmaxf(sqrtf(fmaxf(ss3, 1e-12f)) - 0.5f, 0.f); accl += t * t * wl[s4.w];

    // push (distance) term, once per image, folded into block-0's partial
    if (blockIdx.x == 0 && nl > 1) {
        float push = 0.f;
        for (int p = tid; p < 289; p += TPB) {
            const int i = p / 17, jj = p % 17;
            if (i != jj && i > 0 && jj > 0 && m[i*17+16] > 0.f && m[jj*17+16] > 0.f) {
                float ss = 0.f;
#pragma unroll
                for (int d = 0; d < DD; ++d) {
                    const float df = m[i*17+d] - m[jj*17+d];
                    ss += df * df;
                }
                const float u = fmaxf(1.5f - sqrtf(ss), 0.f);
                push += u * u;
            }
        }
        accl += push / (fmaxf(nlf * (nlf - 1.f), 1.f) * 2.f * (float)BB);
    }

#pragma unroll
    for (int off = 32; off; off >>= 1) accl += __shfl_down(accl, off, 64);
    if ((tid & 63) == 0) wsum[tid >> 6] = accl;
    __syncthreads();
    if (tid == 0)
        vpart[(size_t)b * PBV + blockIdx.x] = wsum[0] + wsum[1] + wsum[2] + wsum[3];
}

__global__ __launch_bounds__(TPB) void k_final(const float* __restrict__ vpart,
                                               float* __restrict__ out) {
    __shared__ float ws4[TPB / 64];
    float v = 0.f;
    for (int i = threadIdx.x; i < BB * PBV; i += TPB) v += vpart[i];
#pragma unroll
    for (int off = 32; off; off >>= 1) v += __shfl_down(v, off, 64);
    if ((threadIdx.x & 63) == 0) ws4[threadIdx.x >> 6] = v;
    __syncthreads();
    if (threadIdx.x == 0) out[0] = ws4[0] + ws4[1] + ws4[2] + ws4[3];
}

extern "C" void kernel_launch(void* const* d_in, const int* in_sizes, int n_in,
                              void* d_out, int out_size, void* d_ws, size_t ws_size,
                              hipStream_t stream) {
    const float* emb = (const float*)d_in[0];
    const int*   seg = (const int*)d_in[1];
    float* out = (float*)d_out;

    int*   acc   = (int*)d_ws;                 // 16*289 ints
    float* vpart = (float*)(acc + BB * 289);   // BB*PBV floats

    hipMemsetAsync(acc, 0, (size_t)BB * 289 * sizeof(int), stream);

    k_accum<<<dim3(PB, BB), TPB, 0, stream>>>(emb, seg, acc);
    k_var  <<<dim3(PBV, BB), TPB, 0, stream>>>(emb, seg, acc, vpart);
    k_final<<<1, TPB, 0, stream>>>(vpart, out);
}